// Round 3
// baseline (1878.011 us; speedup 1.0000x reference)
//
#include <hip/hip_runtime.h>
#include <stdint.h>

#define N_ANCH 193536
#define BATCH  16
#define NCLS   9
#define NBC    (BATCH * NCLS)   // 144
#define TOPK   1000
#define SORTN  4096             // LDS sort width (per bc and per image)
#define MAXDET 100
#define KOFF   0x3C800000u      // 121 << 23; scores in (0.05,1) -> key in (0, 2^26)
#define HBINS  256
#define HSHIFT 18               // key >> 18 -> bin (0.05 -> bin 51, 1.0 -> bin 192)
#define FLOOR_BIN 166u          // score ~0.60; capture floor (correctness-safe: SLOW fallback)
#define CAPBUF 12288            // captured records per (b,c)
#define NMS_SUB 8
#define ROWS_PER_SUB 125        // TOPK / 8
#define NWORDS 16               // 1024 bits per mask row
#define MODE_FAST 1u
#define MODE_SLOW 2u

#define NV4_IMG 435456          // per-image cls float4 count (193536*9/4)
#define P2BLK   48              // K1 blocks per image
#define EV4     9072            // float4 per K1 block (NV4_IMG / P2BLK)
#define NF4_OBJ 774144          // obj float4 count (16*193536/4)

// ---------- exact-arith helpers (mirror reference op order; no FMA contraction) ----

__device__ __forceinline__ float sigm(float x) {
#pragma clang fp contract(off)
    return 1.0f / (1.0f + expf(-x));
}

__device__ __forceinline__ uint32_t score_key(float s) {
    return (s > 0.05f) ? (__float_as_uint(s) - KOFF) : 0u;
}

__device__ __forceinline__ void decode_box(const float* __restrict__ a,
                                           const float* __restrict__ d,
                                           float* bx) {
#pragma clang fp contract(off)
    float a0 = a[0], a1 = a[1], a2 = a[2], a3 = a[3];
    float acx = (a0 + a2) * 0.5f;
    float acy = (a1 + a3) * 0.5f;
    float aw  = fmaxf(a2 - a0, 1.0f);
    float ah  = fmaxf(a3 - a1, 1.0f);
    float cx  = d[0] * aw + acx;
    float cy  = d[1] * ah + acy;
    float w = (float)exp((double)fminf(d[2], 4.0f)) * aw;
    float h = (float)exp((double)fminf(d[3], 4.0f)) * ah;
    bx[0] = cx - w * 0.5f;
    bx[1] = cy - h * 0.5f;
    bx[2] = cx + w * 0.5f;
    bx[3] = cy + h * 0.5f;
}

__device__ __forceinline__ void bitonic_desc(uint64_t* buf, int n, int tid, int nthr) {
    for (int k = 2; k <= n; k <<= 1) {
        for (int j = k >> 1; j > 0; j >>= 1) {
            for (int i = tid; i < n; i += nthr) {
                int ixj = i ^ j;
                if (ixj > i) {
                    uint64_t va = buf[i], vb = buf[ixj];
                    bool up = ((i & k) == 0);          // descending overall
                    if (up ? (va < vb) : (va > vb)) { buf[i] = vb; buf[ixj] = va; }
                }
            }
            __syncthreads();
        }
    }
}

// ---------- K0: sobj = sigmoid(obj), float4; also zero capcnt -------------------

__global__ __launch_bounds__(1024) void sobj_kernel(
    const float* __restrict__ obj, float* __restrict__ sobj,
    uint32_t* __restrict__ capcnt)
{
    int gid = blockIdx.x * 1024 + threadIdx.x;
    if (gid < NBC) capcnt[gid] = 0;
    const float4* o4 = (const float4*)obj;
    float4* s4 = (float4*)sobj;
    for (int i = gid; i < NF4_OBJ; i += gridDim.x * 1024) {
        float4 v = o4[i];
        float4 r;
        r.x = sigm(v.x); r.y = sigm(v.y); r.z = sigm(v.z); r.w = sigm(v.w);
        s4[i] = r;
    }
}

// ---------- K1: single flat float4 stream -> floor-filtered hist + capture -------

__global__ __launch_bounds__(1024) void score_capture_kernel(
    const float* __restrict__ cls, const float* __restrict__ sobj,
    uint32_t* __restrict__ ghist,          // [NBC][HBINS], zeroed
    uint32_t* __restrict__ capcnt,         // [NBC], zeroed
    uint64_t* __restrict__ capbuf)         // [NBC][CAPBUF]
{
    __shared__ uint32_t lh[NCLS * HBINS];  // 9 KB
    const int blk = blockIdx.x, tid = threadIdx.x;
    const int b = blk / P2BLK;
    const size_t base = (size_t)b * NV4_IMG + (size_t)(blk % P2BLK) * EV4;
    const float4* c4 = (const float4*)cls;

    for (int i = tid; i < NCLS * HBINS; i += 1024) lh[i] = 0;
    __syncthreads();

    for (int it = 0; it < 9; ++it) {
        int off = it * 1024 + tid;
        if (off < EV4) {
            float4 v = c4[base + off];
            uint32_t p0 = (uint32_t)((base + off) * 4);
            float vv[4] = {v.x, v.y, v.z, v.w};
            #pragma unroll
            for (int q = 0; q < 4; ++q) {
                uint32_t p = p0 + q;
                uint32_t bn = p / 9u;
                uint32_t c = p - 9u * bn;
                float s = sigm(vv[q]) * sobj[bn];
                uint32_t k = score_key(s);
                uint32_t bin = k >> HSHIFT;
                if (bin >= FLOOR_BIN) {
                    atomicAdd(&lh[(c << 8) + bin], 1u);
                    uint32_t bc = (uint32_t)b * NCLS + c;
                    uint32_t n = bn - (uint32_t)b * N_ANCH;
                    uint32_t slot = atomicAdd(&capcnt[bc], 1u);
                    if (slot < CAPBUF)
                        capbuf[(size_t)bc * CAPBUF + slot] =
                            ((uint64_t)k << 32) | (uint64_t)(0xFFFFFFFFu - n);
                }
            }
        }
    }
    __syncthreads();
    for (int i = tid; i < NCLS * HBINS; i += 1024) {
        uint32_t v = lh[i];
        if (v) atomicAdd(&ghist[(size_t)b * NCLS * HBINS + i], v);
    }
}

// ---------- K2: per-(b,c) pivot bin + FAST/SLOW mode (one wave per block) --------

__global__ __launch_bounds__(64) void pivot_kernel(
    const uint32_t* __restrict__ ghist, const uint32_t* __restrict__ capcnt,
    uint32_t* __restrict__ pivot, uint32_t* __restrict__ mode)
{
    const int blk = blockIdx.x;
    const int lane = threadIdx.x;
    const uint32_t* h = ghist + (size_t)blk * HBINS;
    uint32_t h0 = h[lane * 4 + 0], h1 = h[lane * 4 + 1];
    uint32_t h2 = h[lane * 4 + 2], h3 = h[lane * 4 + 3];
    uint32_t s = h0 + h1 + h2 + h3;
    uint32_t suf = s;                          // S(4l) = count of bins >= 4l
    for (int off = 1; off < 64; off <<= 1) {
        uint32_t o = __shfl_down(suf, off);
        if (lane + off < 64) suf += o;
    }
    uint32_t sufNext = __shfl_down(suf, 1);    // S(4l+4)
    if (lane == 63) sufNext = 0;
    uint32_t S3 = sufNext + h3;
    uint32_t S2 = S3 + h2;
    uint32_t S1 = S2 + h1;
    int d = -1;
    if      (S3 >= TOPK && sufNext < TOPK) d = 4 * lane + 3;
    else if (S2 >= TOPK && S3      < TOPK) d = 4 * lane + 2;
    else if (S1 >= TOPK && S2      < TOPK) d = 4 * lane + 1;
    else if (suf >= TOPK && S1     < TOPK) d = 4 * lane + 0;
    uint64_t fmask = __ballot(d >= 0);
    if (d >= 0) {
        pivot[blk] = (uint32_t)d;              // d >= FLOOR_BIN by construction
        mode[blk] = (capcnt[blk] <= CAPBUF) ? MODE_FAST : MODE_SLOW;
    }
    if (lane == 0 && fmask == 0) mode[blk] = MODE_SLOW;  // <TOPK above floor
}

// ---------- K3: exact fallback for SLOW (b,c) (no-op on this data) ---------------

__global__ __launch_bounds__(256) void slow_kernel(
    const float* __restrict__ cls, const float* __restrict__ obj,
    const uint32_t* __restrict__ mode, uint32_t* __restrict__ pivot,
    uint32_t* __restrict__ capcnt, uint64_t* __restrict__ capbuf)
{
    const int bc = blockIdx.x;
    if (mode[bc] == MODE_FAST) return;
    __shared__ uint32_t h[HBINS];
    __shared__ uint32_t piv;
    const int tid = threadIdx.x;
    const int b = bc / NCLS, c = bc % NCLS;
    if (tid < HBINS) h[tid] = 0;
    __syncthreads();
    for (int n = tid; n < N_ANCH; n += 256) {
        float s = sigm(cls[((size_t)b * N_ANCH + n) * NCLS + c])
                * sigm(obj[(size_t)b * N_ANCH + n]);
        uint32_t k = score_key(s);
        if (k) atomicAdd(&h[k >> HSHIFT], 1u);
    }
    __syncthreads();
    if (tid == 0) {
        uint32_t cum = 0; uint32_t d = 0;
        for (int t = HBINS - 1; t >= 0; --t) {
            if (cum + h[t] >= TOPK) { d = (uint32_t)t; break; }
            cum += h[t];
        }
        piv = d; pivot[bc] = d;
        atomicExch(&capcnt[bc], 0u);
    }
    __syncthreads();
    const uint32_t pv = piv;
    for (int n = tid; n < N_ANCH; n += 256) {
        float s = sigm(cls[((size_t)b * N_ANCH + n) * NCLS + c])
                * sigm(obj[(size_t)b * N_ANCH + n]);
        uint32_t k = score_key(s);
        if (k && (k >> HSHIFT) >= pv) {
            uint32_t slot = atomicAdd(&capcnt[bc], 1u);
            if (slot < CAPBUF)
                capbuf[(size_t)bc * CAPBUF + slot] =
                    ((uint64_t)k << 32) | (uint64_t)(0xFFFFFFFFu - (uint32_t)n);
        }
    }
}

// ---------- K4: filter captured by pivot, sort, emit top-1000 + boxes ------------

__global__ __launch_bounds__(1024) void sort_emit_kernel(
    const uint64_t* __restrict__ capbuf, const uint32_t* __restrict__ capcnt,
    const uint32_t* __restrict__ pivot,
    const float* __restrict__ anchors, const float* __restrict__ deltas,
    float* __restrict__ sel_box, float* __restrict__ sel_score)
{
    __shared__ uint64_t sbuf[SORTN];        // 32 KB
    __shared__ uint32_t lcnt;
    const int blk = blockIdx.x, tid = threadIdx.x;
    const int b = blk / NCLS;
    const uint32_t cnt = min(capcnt[blk], (uint32_t)CAPBUF);
    const uint32_t pv = pivot[blk];
    for (int i = tid; i < SORTN; i += 1024) sbuf[i] = 0;
    if (tid == 0) lcnt = 0;
    __syncthreads();
    for (int i = tid; (uint32_t)i < cnt; i += 1024) {
        uint64_t e = capbuf[(size_t)blk * CAPBUF + i];
        if (((uint32_t)(e >> 32) >> HSHIFT) >= pv) {
            uint32_t s = atomicAdd(&lcnt, 1u);
            if (s < SORTN) sbuf[s] = e;
        }
    }
    __syncthreads();
    bitonic_desc(sbuf, SORTN, tid, 1024);
    if (tid < TOPK) {
        uint64_t e = sbuf[tid];
        uint32_t k = (uint32_t)(e >> 32);
        float bx[4] = {0.f, 0.f, 0.f, 0.f};
        float score = 0.f;
        if (k) {
            uint32_t idx = 0xFFFFFFFFu - (uint32_t)(e & 0xFFFFFFFFu);
            score = __uint_as_float(k + KOFF);
            decode_box(anchors + (size_t)idx * 4,
                       deltas + ((size_t)b * N_ANCH + idx) * 4, bx);
        }
        sel_score[(size_t)blk * TOPK + tid] = score;
        float* o = sel_box + ((size_t)blk * TOPK + tid) * 4;
        o[0] = bx[0]; o[1] = bx[1]; o[2] = bx[2]; o[3] = bx[3];
    }
}

// ---------- K5: suppression bitmask build (8 blocks per (b,c)) -------------------
// bit-exact div-free compare: fl32(inter/uni) > 0.5f  <=>  inter > (0.5+2^-25)*uni

__global__ __launch_bounds__(1024) void mask_build_kernel(
    const float* __restrict__ sel_box, uint64_t* __restrict__ gmask)
{
    __shared__ float X0[1024], Y0[1024], X1[1024], Y1[1024], AR[1024];
    const int blk = blockIdx.x, tid = threadIdx.x;
    const int bc = blk >> 3, sub = blk & 7;
    const int lane = tid & 63, w = tid >> 6;
    {
        float x0 = 0, y0 = 0, x1 = 0, y1 = 0, a = 0;
        if (tid < TOPK) {
#pragma clang fp contract(off)
            const float* p = sel_box + ((size_t)bc * TOPK + tid) * 4;
            x0 = p[0]; y0 = p[1]; x1 = p[2]; y1 = p[3];
            a = (x1 - x0) * (y1 - y0);
        }
        X0[tid] = x0; Y0[tid] = y0; X1[tid] = x1; Y1[tid] = y1; AR[tid] = a;
    }
    __syncthreads();

    for (int r = sub * ROWS_PER_SUB + w; r < (sub + 1) * ROWS_PER_SUB; r += 16) {
        float rx0 = X0[r], ry0 = Y0[r], rx1 = X1[r], ry1 = Y1[r], ra = AR[r];
        int wf = r >> 6;
        uint64_t* rowp = gmask + ((size_t)bc * TOPK + r) * NWORDS;
        for (int ww = 0; ww < wf; ++ww)
            if (lane == 0) rowp[ww] = 0;
        for (int ww = wf; ww < NWORDS; ++ww) {
            int j = ww * 64 + lane;
            bool pred = false;
            if (j > r && j < TOPK) {
#pragma clang fp contract(off)
                float xx0 = fmaxf(rx0, X0[j]);
                float yy0 = fmaxf(ry0, Y0[j]);
                float xx1 = fminf(rx1, X1[j]);
                float yy1 = fminf(ry1, Y1[j]);
                float iw = fmaxf(xx1 - xx0, 0.0f);
                float ih = fmaxf(yy1 - yy0, 0.0f);
                float inter = iw * ih;
                float uni = fmaxf((ra + AR[j]) - inter, 1e-6f);
                pred = ((double)inter > 0x1.000001p-1 * (double)uni);
            }
            uint64_t m = __ballot(pred);
            if (lane == 0) rowp[ww] = m;
        }
    }
}

// ---------- K6: greedy scan over bitmask (LDS-staged, one wave, ring prefetch) ---

__global__ __launch_bounds__(1024) void greedy_kernel(
    const uint64_t* __restrict__ gmask, const float* __restrict__ sel_score,
    float* __restrict__ final_score)
{
    __shared__ uint64_t lmask[TOPK * NWORDS];   // 125 KB
    __shared__ uint64_t remOut[NWORDS];
    const int blk = blockIdx.x, tid = threadIdx.x;
    for (int i = tid; i < TOPK * NWORDS; i += 1024)
        lmask[i] = gmask[(size_t)blk * TOPK * NWORDS + i];
    __syncthreads();

    if (tid < 64) {
        const int lane = tid;
        uint64_t rem = 0;                 // lane w < 16 owns removed-word w
        uint64_t ring[16];
        #pragma unroll
        for (int u = 0; u < 16; ++u)
            ring[u] = (lane < NWORDS) ? lmask[u * NWORDS + lane] : 0;
        for (int ib = 0; ib < TOPK; ib += 16) {
            #pragma unroll
            for (int u = 0; u < 16; ++u) {
                int i = ib + u;
                if (i < TOPK) {
                    uint64_t row = ring[u];
                    int ipf = i + 16;
                    ring[u] = (lane < NWORDS && ipf < TOPK) ? lmask[ipf * NWORDS + lane] : 0;
                    int wi = i >> 6;
                    uint32_t lo = (uint32_t)__builtin_amdgcn_readlane((int)(uint32_t)rem, wi);
                    uint32_t hi = (uint32_t)__builtin_amdgcn_readlane((int)(uint32_t)(rem >> 32), wi);
                    uint64_t wv = ((uint64_t)hi << 32) | lo;
                    if (!((wv >> (i & 63)) & 1ull)) rem |= row;
                }
            }
        }
        if (lane < NWORDS) remOut[lane] = rem;
    }
    __syncthreads();

    if (tid < TOPK) {
        bool kept = !((remOut[tid >> 6] >> (tid & 63)) & 1ull);
        float s = sel_score[(size_t)blk * TOPK + tid];
        final_score[(size_t)blk * TOPK + tid] = (kept && s > 0.05f) ? s : 0.0f;
    }
}

// ---------- K7: per-image top-100 (hist-select + bitonic; exact tie semantics) ---

__global__ __launch_bounds__(1024) void final_kernel(
    const float* __restrict__ final_score, const float* __restrict__ sel_box,
    float* __restrict__ out)                // [BATCH][MAXDET][6]
{
    __shared__ float sc[NCLS * TOPK];       // 36 KB
    __shared__ uint32_t h[4096];            // 16 KB
    __shared__ uint32_t chunk[1024];
    __shared__ uint64_t sbuf[SORTN];        // 32 KB
    __shared__ int sh_d, sh_fb;
    __shared__ uint32_t cnt;
    const int b = blockIdx.x, tid = threadIdx.x;

    for (int i = tid; i < 4096; i += 1024) h[i] = 0;
    for (int t = tid; t < NCLS * TOPK; t += 1024)
        sc[t] = final_score[(size_t)b * NCLS * TOPK + t];
    if (tid == 0) cnt = 0;
    __syncthreads();

    for (int t = tid; t < NCLS * TOPK; t += 1024) {
        uint32_t bits = __float_as_uint(sc[t]);
        if (bits) atomicAdd(&h[bits >> HSHIFT], 1u);
    }
    __syncthreads();
    chunk[tid] = h[tid * 4] + h[tid * 4 + 1] + h[tid * 4 + 2] + h[tid * 4 + 3];
    __syncthreads();
    if (tid == 0) {
        int d = -1; uint32_t cum = 0;
        for (int t = 1023; t >= 0; --t) {
            if (cum + chunk[t] >= MAXDET) {
                for (int j = 3; j >= 0; --j) {
                    uint32_t v = h[t * 4 + j];
                    if (cum + v >= MAXDET) { d = t * 4 + j; goto found; }
                    cum += v;
                }
            }
            cum += chunk[t];
        }
found:
        if (d < 0) { sh_d = 0; sh_fb = 1; }
        else       { sh_d = d; sh_fb = 0; }
    }
    __syncthreads();
    const int d = sh_d, fb = sh_fb;

    for (int t = tid; t < NCLS * TOPK; t += 1024) {
        uint32_t bits = __float_as_uint(sc[t]);
        bool take = fb ? (bits != 0 || t < 1024)
                       : (bits != 0 && (bits >> HSHIFT) >= (uint32_t)d);
        if (take) {
            uint32_t slot = atomicAdd(&cnt, 1u);
            if (slot < SORTN)
                sbuf[slot] = ((uint64_t)bits << 32) | (uint64_t)(0xFFFFFFFFu - (uint32_t)t);
        }
    }
    __syncthreads();
    uint32_t c2 = min(cnt, (uint32_t)SORTN);
    for (int i = tid; i < SORTN; i += 1024)
        if ((uint32_t)i >= c2) sbuf[i] = 0;
    __syncthreads();
    bitonic_desc(sbuf, SORTN, tid, 1024);

    if (tid < MAXDET) {
        uint64_t e = sbuf[tid];
        uint32_t bits = (uint32_t)(e >> 32);
        uint32_t flat = 0xFFFFFFFFu - (uint32_t)(e & 0xFFFFFFFFu);
        float bx[4] = {0.f, 0.f, 0.f, 0.f};
        float sval = 0.f, lab = 0.f;
        if (flat < NCLS * TOPK) {
            const float* bp = sel_box + ((size_t)b * NCLS * TOPK + flat) * 4;
            bx[0] = bp[0]; bx[1] = bp[1]; bx[2] = bp[2]; bx[3] = bp[3];
            sval = __uint_as_float(bits);
            lab = (float)(flat / TOPK);
        }
        float* o = out + ((size_t)b * MAXDET + tid) * 6;
        o[0] = bx[0]; o[1] = bx[1]; o[2] = bx[2]; o[3] = bx[3];
        o[4] = sval;  o[5] = lab;
    }
}

// ---------------------------------- launcher -----------------------------------

extern "C" void kernel_launch(void* const* d_in, const int* in_sizes, int n_in,
                              void* d_out, int out_size, void* d_ws, size_t ws_size,
                              hipStream_t stream) {
    const float* anchors = (const float*)d_in[0];
    const float* deltas  = (const float*)d_in[1];
    const float* cls     = (const float*)d_in[2];
    const float* obj     = (const float*)d_in[3];
    float* out = (float*)d_out;

    // workspace layout (~30.2 MB).
    //   [0, 12.39M)          sobj        (dies after K1)
    //   [12.39M, 26.55M)     capbuf      (dies after K4)
    //   [0, 18.44M)          gmask       (overlay; born K5, after both die)
    //   persistent tail: ghist, pivot/capcnt/mode, sel_box, sel_score, final_sc
    char* ws = (char*)d_ws;
    const size_t SOBJ_B   = (size_t)BATCH * N_ANCH * 4;            // 12,386,304
    const size_t CAPB_B   = (size_t)NBC * CAPBUF * 8;              // 14,155,776
    float*    sobj   = (float*)ws;
    uint64_t* capbuf = (uint64_t*)(ws + SOBJ_B);
    uint64_t* gmask  = (uint64_t*)ws;                              // overlay
    char* tail = ws + SOBJ_B + CAPB_B;                             // 26,542,080
    uint32_t* ghist  = (uint32_t*)tail;                            // 147,456
    uint32_t* pivot  = (uint32_t*)(tail + 147456);
    uint32_t* capcnt = (uint32_t*)(tail + 147456 + 576);
    uint32_t* mode   = (uint32_t*)(tail + 147456 + 1152);
    float* sel_box   = (float*)(tail + 147456 + 1728);             // 2,304,000
    float* sel_score = sel_box + (size_t)NBC * TOPK * 4;           // 576,000
    float* final_sc  = sel_score + (size_t)NBC * TOPK;             // 576,000

    hipMemsetAsync(ghist, 0, (size_t)NBC * HBINS * 4, stream);

    sobj_kernel<<<dim3(512), dim3(1024), 0, stream>>>(obj, sobj, capcnt);
    score_capture_kernel<<<dim3(BATCH * P2BLK), dim3(1024), 0, stream>>>(
        cls, sobj, ghist, capcnt, capbuf);
    pivot_kernel<<<dim3(NBC), dim3(64), 0, stream>>>(ghist, capcnt, pivot, mode);
    slow_kernel<<<dim3(NBC), dim3(256), 0, stream>>>(cls, obj, mode, pivot, capcnt, capbuf);
    sort_emit_kernel<<<dim3(NBC), dim3(1024), 0, stream>>>(capbuf, capcnt, pivot,
                                                           anchors, deltas,
                                                           sel_box, sel_score);
    mask_build_kernel<<<dim3(NBC * NMS_SUB), dim3(1024), 0, stream>>>(sel_box, gmask);
    greedy_kernel<<<dim3(NBC), dim3(1024), 0, stream>>>(gmask, sel_score, final_sc);
    final_kernel<<<dim3(BATCH), dim3(1024), 0, stream>>>(final_sc, sel_box, out);
}

// Round 4
// 569.594 us; speedup vs baseline: 3.2971x; 3.2971x over previous
//
#include <hip/hip_runtime.h>
#include <stdint.h>

#define N_ANCH 193536
#define BATCH  16
#define NCLS   9
#define NBC    (BATCH * NCLS)   // 144
#define TOPK   1000
#define SORTN  4096             // LDS sort width (per bc and per image)
#define MAXDET 100
#define KOFF   0x3C800000u      // 121 << 23; scores in (0.05,1) -> key in (0, 2^26)
#define HBINS  256
#define HSHIFT 18               // key >> 18 -> bin (0.05 -> bin 51, 1.0 -> bin 192)
#define FLOOR_BIN 166u          // score ~0.59; capture floor (correctness-safe: SLOW fallback)
#define CAPBUF 12288            // captured records per (b,c)
#define SBUF   4096             // per-block LDS staging records
#define NMS_SUB 8
#define ROWS_PER_SUB 125        // TOPK / 8
#define NWORDS 16               // 1024 bits per mask row
#define MODE_FAST 1u
#define MODE_SLOW 2u
#define OVF_BIT 0x40000000u

#define NV4_IMG 435456          // per-image cls float4 count (193536*9/4)
#define P2BLK   48              // K1 blocks per image
#define EV4     9072            // float4 per K1 block (NV4_IMG / P2BLK)
#define NF4_OBJ 774144          // obj float4 count (16*193536/4)

// ---------- exact-arith helpers (mirror reference op order; no FMA contraction) ----

__device__ __forceinline__ float sigm(float x) {
#pragma clang fp contract(off)
    return 1.0f / (1.0f + expf(-x));
}

__device__ __forceinline__ uint32_t score_key(float s) {
    return (s > 0.05f) ? (__float_as_uint(s) - KOFF) : 0u;
}

__device__ __forceinline__ void decode_box(const float* __restrict__ a,
                                           const float* __restrict__ d,
                                           float* bx) {
#pragma clang fp contract(off)
    float a0 = a[0], a1 = a[1], a2 = a[2], a3 = a[3];
    float acx = (a0 + a2) * 0.5f;
    float acy = (a1 + a3) * 0.5f;
    float aw  = fmaxf(a2 - a0, 1.0f);
    float ah  = fmaxf(a3 - a1, 1.0f);
    float cx  = d[0] * aw + acx;
    float cy  = d[1] * ah + acy;
    float w = (float)exp((double)fminf(d[2], 4.0f)) * aw;
    float h = (float)exp((double)fminf(d[3], 4.0f)) * ah;
    bx[0] = cx - w * 0.5f;
    bx[1] = cy - h * 0.5f;
    bx[2] = cx + w * 0.5f;
    bx[3] = cy + h * 0.5f;
}

__device__ __forceinline__ void bitonic_desc(uint64_t* buf, int n, int tid, int nthr) {
    for (int k = 2; k <= n; k <<= 1) {
        for (int j = k >> 1; j > 0; j >>= 1) {
            for (int i = tid; i < n; i += nthr) {
                int ixj = i ^ j;
                if (ixj > i) {
                    uint64_t va = buf[i], vb = buf[ixj];
                    bool up = ((i & k) == 0);          // descending overall
                    if (up ? (va < vb) : (va > vb)) { buf[i] = vb; buf[ixj] = va; }
                }
            }
            __syncthreads();
        }
    }
}

// ---------- K0: sobj = sigmoid(obj), float4; also zero capcnt -------------------

__global__ __launch_bounds__(1024) void sobj_kernel(
    const float* __restrict__ obj, float* __restrict__ sobj,
    uint32_t* __restrict__ capcnt)
{
    int gid = blockIdx.x * 1024 + threadIdx.x;
    if (gid < NBC) capcnt[gid] = 0;
    const float4* o4 = (const float4*)obj;
    float4* s4 = (float4*)sobj;
    for (int i = gid; i < NF4_OBJ; i += gridDim.x * 1024) {
        float4 v = o4[i];
        float4 r;
        r.x = sigm(v.x); r.y = sigm(v.y); r.z = sigm(v.z); r.w = sigm(v.w);
        s4[i] = r;
    }
}

// ---------- K1: flat float4 stream -> floor-filtered hist + LDS-staged capture ---
// No per-item global atomics: wave-ballot aggregation into LDS stage, then one
// global reservation per class per block.

__global__ __launch_bounds__(1024) void score_capture_kernel(
    const float* __restrict__ cls, const float* __restrict__ sobj,
    uint32_t* __restrict__ ghist,          // [NBC][HBINS], zeroed
    uint32_t* __restrict__ capcnt,         // [NBC], zeroed
    uint64_t* __restrict__ capbuf)         // [NBC][CAPBUF]
{
    __shared__ uint32_t lh[NCLS * HBINS];  // 9 KB
    __shared__ uint64_t stage[SBUF];       // 32 KB: (k<<22)|(c<<18)|n
    __shared__ uint32_t scnt;
    __shared__ uint32_t ccnt[NCLS];
    __shared__ uint32_t cwrite[NCLS];
    const int blk = blockIdx.x, tid = threadIdx.x;
    const int b = blk / P2BLK;
    const size_t base = (size_t)b * NV4_IMG + (size_t)(blk % P2BLK) * EV4;
    const float4* c4 = (const float4*)cls;
    const int lane = tid & 63;

    for (int i = tid; i < NCLS * HBINS; i += 1024) lh[i] = 0;
    if (tid < NCLS) ccnt[tid] = 0;
    if (tid == 0) scnt = 0;
    __syncthreads();

    for (int it = 0; it < 9; ++it) {
        int off = it * 1024 + tid;
        bool inr = (off < EV4);
        int offc = inr ? off : (EV4 - 1);
        float4 v = c4[base + offc];
        uint32_t p0 = (uint32_t)((base + offc) * 4);
        float vv[4] = {v.x, v.y, v.z, v.w};
        #pragma unroll
        for (int q = 0; q < 4; ++q) {
            uint32_t p = p0 + q;
            uint32_t bn = p / 9u;
            uint32_t c = p - 9u * bn;
            float s = sigm(vv[q]) * sobj[bn];
            uint32_t k = score_key(s);
            uint32_t bin = k >> HSHIFT;
            bool cap = inr && (bin >= FLOOR_BIN);
            uint64_t m = __ballot(cap);
            if (m) {
                uint32_t tot = (uint32_t)__popcll(m);
                int fl = __ffsll((unsigned long long)m) - 1;
                uint32_t wbase = 0;
                if (lane == fl) wbase = atomicAdd(&scnt, tot);
                wbase = __shfl(wbase, fl);
                if (cap) {
                    uint32_t slot = wbase +
                        (uint32_t)__popcll(m & ((1ull << lane) - 1ull));
                    uint32_t n = bn - (uint32_t)b * N_ANCH;
                    if (slot < SBUF)
                        stage[slot] = ((uint64_t)k << 22) | ((uint64_t)c << 18)
                                    | (uint64_t)n;
                    atomicAdd(&lh[(c << 8) + bin], 1u);
                    atomicAdd(&ccnt[c], 1u);
                }
            }
        }
    }
    __syncthreads();

    const uint32_t total = scnt;
    const uint32_t nstage = min(total, (uint32_t)SBUF);
    const bool ovf = (total > SBUF);
    if (tid < NCLS) {
        uint32_t bc = (uint32_t)b * NCLS + tid;
        uint32_t cb = atomicAdd(&capcnt[bc], ccnt[tid]);   // one reservation / class
        if (ovf) atomicOr(&capcnt[bc], OVF_BIT);           // force SLOW for this image
        cwrite[tid] = cb;
    }
    __syncthreads();

    for (uint32_t i = tid; i < nstage; i += 1024) {
        uint64_t r = stage[i];
        uint32_t c = (uint32_t)(r >> 18) & 15u;
        uint32_t n = (uint32_t)(r & 0x3FFFFu);
        uint32_t k = (uint32_t)(r >> 22);
        uint32_t slot = atomicAdd(&cwrite[c], 1u);         // LDS: global slot index
        if (slot < CAPBUF)
            capbuf[(size_t)((uint32_t)b * NCLS + c) * CAPBUF + slot] =
                ((uint64_t)k << 32) | (uint64_t)(0xFFFFFFFFu - n);
    }

    for (int i = tid; i < NCLS * HBINS; i += 1024) {
        uint32_t v = lh[i];
        if (v) atomicAdd(&ghist[(size_t)b * NCLS * HBINS + i], v);
    }
}

// ---------- K2: per-(b,c) pivot bin + FAST/SLOW mode (one wave per block) --------

__global__ __launch_bounds__(64) void pivot_kernel(
    const uint32_t* __restrict__ ghist, const uint32_t* __restrict__ capcnt,
    uint32_t* __restrict__ pivot, uint32_t* __restrict__ mode)
{
    const int blk = blockIdx.x;
    const int lane = threadIdx.x;
    const uint32_t* h = ghist + (size_t)blk * HBINS;
    uint32_t h0 = h[lane * 4 + 0], h1 = h[lane * 4 + 1];
    uint32_t h2 = h[lane * 4 + 2], h3 = h[lane * 4 + 3];
    uint32_t s = h0 + h1 + h2 + h3;
    uint32_t suf = s;                          // S(4l) = count of bins >= 4l
    for (int off = 1; off < 64; off <<= 1) {
        uint32_t o = __shfl_down(suf, off);
        if (lane + off < 64) suf += o;
    }
    uint32_t sufNext = __shfl_down(suf, 1);    // S(4l+4)
    if (lane == 63) sufNext = 0;
    uint32_t S3 = sufNext + h3;
    uint32_t S2 = S3 + h2;
    uint32_t S1 = S2 + h1;
    int d = -1;
    if      (S3 >= TOPK && sufNext < TOPK) d = 4 * lane + 3;
    else if (S2 >= TOPK && S3      < TOPK) d = 4 * lane + 2;
    else if (S1 >= TOPK && S2      < TOPK) d = 4 * lane + 1;
    else if (suf >= TOPK && S1     < TOPK) d = 4 * lane + 0;
    uint64_t fmask = __ballot(d >= 0);
    if (d >= 0) {
        pivot[blk] = (uint32_t)d;              // d >= FLOOR_BIN by construction
        mode[blk] = (capcnt[blk] <= CAPBUF) ? MODE_FAST : MODE_SLOW;
    }
    if (lane == 0 && fmask == 0) mode[blk] = MODE_SLOW;  // <TOPK above floor
}

// ---------- K3: exact fallback for SLOW (b,c) (no-op on this data) ---------------

__global__ __launch_bounds__(256) void slow_kernel(
    const float* __restrict__ cls, const float* __restrict__ obj,
    const uint32_t* __restrict__ mode, uint32_t* __restrict__ pivot,
    uint32_t* __restrict__ capcnt, uint64_t* __restrict__ capbuf)
{
    const int bc = blockIdx.x;
    if (mode[bc] == MODE_FAST) return;
    __shared__ uint32_t h[HBINS];
    __shared__ uint32_t piv;
    const int tid = threadIdx.x;
    const int b = bc / NCLS, c = bc % NCLS;
    if (tid < HBINS) h[tid] = 0;
    __syncthreads();
    for (int n = tid; n < N_ANCH; n += 256) {
        float s = sigm(cls[((size_t)b * N_ANCH + n) * NCLS + c])
                * sigm(obj[(size_t)b * N_ANCH + n]);
        uint32_t k = score_key(s);
        if (k) atomicAdd(&h[k >> HSHIFT], 1u);
    }
    __syncthreads();
    if (tid == 0) {
        uint32_t cum = 0; uint32_t d = 0;
        for (int t = HBINS - 1; t >= 0; --t) {
            if (cum + h[t] >= TOPK) { d = (uint32_t)t; break; }
            cum += h[t];
        }
        piv = d; pivot[bc] = d;
        atomicExch(&capcnt[bc], 0u);
    }
    __syncthreads();
    const uint32_t pv = piv;
    for (int n = tid; n < N_ANCH; n += 256) {
        float s = sigm(cls[((size_t)b * N_ANCH + n) * NCLS + c])
                * sigm(obj[(size_t)b * N_ANCH + n]);
        uint32_t k = score_key(s);
        if (k && (k >> HSHIFT) >= pv) {
            uint32_t slot = atomicAdd(&capcnt[bc], 1u);
            if (slot < CAPBUF)
                capbuf[(size_t)bc * CAPBUF + slot] =
                    ((uint64_t)k << 32) | (uint64_t)(0xFFFFFFFFu - (uint32_t)n);
        }
    }
}

// ---------- K4: filter captured by pivot, sort, emit top-1000 + boxes ------------

__global__ __launch_bounds__(1024) void sort_emit_kernel(
    const uint64_t* __restrict__ capbuf, const uint32_t* __restrict__ capcnt,
    const uint32_t* __restrict__ pivot,
    const float* __restrict__ anchors, const float* __restrict__ deltas,
    float* __restrict__ sel_box, float* __restrict__ sel_score)
{
    __shared__ uint64_t sbuf[SORTN];        // 32 KB
    __shared__ uint32_t lcnt;
    const int blk = blockIdx.x, tid = threadIdx.x;
    const int b = blk / NCLS;
    const uint32_t cnt = min(capcnt[blk] & ~OVF_BIT, (uint32_t)CAPBUF);
    const uint32_t pv = pivot[blk];
    for (int i = tid; i < SORTN; i += 1024) sbuf[i] = 0;
    if (tid == 0) lcnt = 0;
    __syncthreads();
    for (int i = tid; (uint32_t)i < cnt; i += 1024) {
        uint64_t e = capbuf[(size_t)blk * CAPBUF + i];
        if (((uint32_t)(e >> 32) >> HSHIFT) >= pv) {
            uint32_t s = atomicAdd(&lcnt, 1u);
            if (s < SORTN) sbuf[s] = e;
        }
    }
    __syncthreads();
    bitonic_desc(sbuf, SORTN, tid, 1024);
    if (tid < TOPK) {
        uint64_t e = sbuf[tid];
        uint32_t k = (uint32_t)(e >> 32);
        float bx[4] = {0.f, 0.f, 0.f, 0.f};
        float score = 0.f;
        if (k) {
            uint32_t idx = 0xFFFFFFFFu - (uint32_t)(e & 0xFFFFFFFFu);
            score = __uint_as_float(k + KOFF);
            decode_box(anchors + (size_t)idx * 4,
                       deltas + ((size_t)b * N_ANCH + idx) * 4, bx);
        }
        sel_score[(size_t)blk * TOPK + tid] = score;
        float* o = sel_box + ((size_t)blk * TOPK + tid) * 4;
        o[0] = bx[0]; o[1] = bx[1]; o[2] = bx[2]; o[3] = bx[3];
    }
}

// ---------- K5: suppression bitmask build (8 blocks per (b,c)) -------------------
// bit-exact div-free compare: fl32(inter/uni) > 0.5f  <=>  inter > (0.5+2^-25)*uni

__global__ __launch_bounds__(1024) void mask_build_kernel(
    const float* __restrict__ sel_box, uint64_t* __restrict__ gmask)
{
    __shared__ float X0[1024], Y0[1024], X1[1024], Y1[1024], AR[1024];
    const int blk = blockIdx.x, tid = threadIdx.x;
    const int bc = blk >> 3, sub = blk & 7;
    const int lane = tid & 63, w = tid >> 6;
    {
        float x0 = 0, y0 = 0, x1 = 0, y1 = 0, a = 0;
        if (tid < TOPK) {
#pragma clang fp contract(off)
            const float* p = sel_box + ((size_t)bc * TOPK + tid) * 4;
            x0 = p[0]; y0 = p[1]; x1 = p[2]; y1 = p[3];
            a = (x1 - x0) * (y1 - y0);
        }
        X0[tid] = x0; Y0[tid] = y0; X1[tid] = x1; Y1[tid] = y1; AR[tid] = a;
    }
    __syncthreads();

    for (int r = sub * ROWS_PER_SUB + w; r < (sub + 1) * ROWS_PER_SUB; r += 16) {
        float rx0 = X0[r], ry0 = Y0[r], rx1 = X1[r], ry1 = Y1[r], ra = AR[r];
        int wf = r >> 6;
        uint64_t* rowp = gmask + ((size_t)bc * TOPK + r) * NWORDS;
        for (int ww = 0; ww < wf; ++ww)
            if (lane == 0) rowp[ww] = 0;
        for (int ww = wf; ww < NWORDS; ++ww) {
            int j = ww * 64 + lane;
            bool pred = false;
            if (j > r && j < TOPK) {
#pragma clang fp contract(off)
                float xx0 = fmaxf(rx0, X0[j]);
                float yy0 = fmaxf(ry0, Y0[j]);
                float xx1 = fminf(rx1, X1[j]);
                float yy1 = fminf(ry1, Y1[j]);
                float iw = fmaxf(xx1 - xx0, 0.0f);
                float ih = fmaxf(yy1 - yy0, 0.0f);
                float inter = iw * ih;
                float uni = fmaxf((ra + AR[j]) - inter, 1e-6f);
                pred = ((double)inter > 0x1.000001p-1 * (double)uni);
            }
            uint64_t m = __ballot(pred);
            if (lane == 0) rowp[ww] = m;
        }
    }
}

// ---------- K6: greedy scan over bitmask (LDS-staged, one wave, ring prefetch) ---

__global__ __launch_bounds__(1024) void greedy_kernel(
    const uint64_t* __restrict__ gmask, const float* __restrict__ sel_score,
    float* __restrict__ final_score)
{
    __shared__ uint64_t lmask[TOPK * NWORDS];   // 125 KB
    __shared__ uint64_t remOut[NWORDS];
    const int blk = blockIdx.x, tid = threadIdx.x;
    for (int i = tid; i < TOPK * NWORDS; i += 1024)
        lmask[i] = gmask[(size_t)blk * TOPK * NWORDS + i];
    __syncthreads();

    if (tid < 64) {
        const int lane = tid;
        uint64_t rem = 0;                 // lane w < 16 owns removed-word w
        uint64_t ring[16];
        #pragma unroll
        for (int u = 0; u < 16; ++u)
            ring[u] = (lane < NWORDS) ? lmask[u * NWORDS + lane] : 0;
        for (int ib = 0; ib < TOPK; ib += 16) {
            #pragma unroll
            for (int u = 0; u < 16; ++u) {
                int i = ib + u;
                if (i < TOPK) {
                    uint64_t row = ring[u];
                    int ipf = i + 16;
                    ring[u] = (lane < NWORDS && ipf < TOPK) ? lmask[ipf * NWORDS + lane] : 0;
                    int wi = i >> 6;
                    uint32_t lo = (uint32_t)__builtin_amdgcn_readlane((int)(uint32_t)rem, wi);
                    uint32_t hi = (uint32_t)__builtin_amdgcn_readlane((int)(uint32_t)(rem >> 32), wi);
                    uint64_t wv = ((uint64_t)hi << 32) | lo;
                    if (!((wv >> (i & 63)) & 1ull)) rem |= row;
                }
            }
        }
        if (lane < NWORDS) remOut[lane] = rem;
    }
    __syncthreads();

    if (tid < TOPK) {
        bool kept = !((remOut[tid >> 6] >> (tid & 63)) & 1ull);
        float s = sel_score[(size_t)blk * TOPK + tid];
        final_score[(size_t)blk * TOPK + tid] = (kept && s > 0.05f) ? s : 0.0f;
    }
}

// ---------- K7: per-image top-100 (hist-select + bitonic; exact tie semantics) ---

__global__ __launch_bounds__(1024) void final_kernel(
    const float* __restrict__ final_score, const float* __restrict__ sel_box,
    float* __restrict__ out)                // [BATCH][MAXDET][6]
{
    __shared__ float sc[NCLS * TOPK];       // 36 KB
    __shared__ uint32_t h[4096];            // 16 KB
    __shared__ uint32_t chunk[1024];
    __shared__ uint64_t sbuf[SORTN];        // 32 KB
    __shared__ int sh_d, sh_fb;
    __shared__ uint32_t cnt;
    const int b = blockIdx.x, tid = threadIdx.x;

    for (int i = tid; i < 4096; i += 1024) h[i] = 0;
    for (int t = tid; t < NCLS * TOPK; t += 1024)
        sc[t] = final_score[(size_t)b * NCLS * TOPK + t];
    if (tid == 0) cnt = 0;
    __syncthreads();

    for (int t = tid; t < NCLS * TOPK; t += 1024) {
        uint32_t bits = __float_as_uint(sc[t]);
        if (bits) atomicAdd(&h[bits >> HSHIFT], 1u);
    }
    __syncthreads();
    chunk[tid] = h[tid * 4] + h[tid * 4 + 1] + h[tid * 4 + 2] + h[tid * 4 + 3];
    __syncthreads();
    if (tid == 0) {
        int d = -1; uint32_t cum = 0;
        for (int t = 1023; t >= 0; --t) {
            if (cum + chunk[t] >= MAXDET) {
                for (int j = 3; j >= 0; --j) {
                    uint32_t v = h[t * 4 + j];
                    if (cum + v >= MAXDET) { d = t * 4 + j; goto found; }
                    cum += v;
                }
            }
            cum += chunk[t];
        }
found:
        if (d < 0) { sh_d = 0; sh_fb = 1; }
        else       { sh_d = d; sh_fb = 0; }
    }
    __syncthreads();
    const int d = sh_d, fb = sh_fb;

    for (int t = tid; t < NCLS * TOPK; t += 1024) {
        uint32_t bits = __float_as_uint(sc[t]);
        bool take = fb ? (bits != 0 || t < 1024)
                       : (bits != 0 && (bits >> HSHIFT) >= (uint32_t)d);
        if (take) {
            uint32_t slot = atomicAdd(&cnt, 1u);
            if (slot < SORTN)
                sbuf[slot] = ((uint64_t)bits << 32) | (uint64_t)(0xFFFFFFFFu - (uint32_t)t);
        }
    }
    __syncthreads();
    uint32_t c2 = min(cnt, (uint32_t)SORTN);
    for (int i = tid; i < SORTN; i += 1024)
        if ((uint32_t)i >= c2) sbuf[i] = 0;
    __syncthreads();
    bitonic_desc(sbuf, SORTN, tid, 1024);

    if (tid < MAXDET) {
        uint64_t e = sbuf[tid];
        uint32_t bits = (uint32_t)(e >> 32);
        uint32_t flat = 0xFFFFFFFFu - (uint32_t)(e & 0xFFFFFFFFu);
        float bx[4] = {0.f, 0.f, 0.f, 0.f};
        float sval = 0.f, lab = 0.f;
        if (flat < NCLS * TOPK) {
            const float* bp = sel_box + ((size_t)b * NCLS * TOPK + flat) * 4;
            bx[0] = bp[0]; bx[1] = bp[1]; bx[2] = bp[2]; bx[3] = bp[3];
            sval = __uint_as_float(bits);
            lab = (float)(flat / TOPK);
        }
        float* o = out + ((size_t)b * MAXDET + tid) * 6;
        o[0] = bx[0]; o[1] = bx[1]; o[2] = bx[2]; o[3] = bx[3];
        o[4] = sval;  o[5] = lab;
    }
}

// ---------------------------------- launcher -----------------------------------

extern "C" void kernel_launch(void* const* d_in, const int* in_sizes, int n_in,
                              void* d_out, int out_size, void* d_ws, size_t ws_size,
                              hipStream_t stream) {
    const float* anchors = (const float*)d_in[0];
    const float* deltas  = (const float*)d_in[1];
    const float* cls     = (const float*)d_in[2];
    const float* obj     = (const float*)d_in[3];
    float* out = (float*)d_out;

    // workspace layout (~30.2 MB).
    //   [0, 12.39M)          sobj        (dies after K1)
    //   [12.39M, 26.55M)     capbuf      (dies after K4)
    //   [0, 18.44M)          gmask       (overlay; born K5, after both die)
    //   persistent tail: ghist, pivot/capcnt/mode, sel_box, sel_score, final_sc
    char* ws = (char*)d_ws;
    const size_t SOBJ_B   = (size_t)BATCH * N_ANCH * 4;            // 12,386,304
    const size_t CAPB_B   = (size_t)NBC * CAPBUF * 8;              // 14,155,776
    float*    sobj   = (float*)ws;
    uint64_t* capbuf = (uint64_t*)(ws + SOBJ_B);
    uint64_t* gmask  = (uint64_t*)ws;                              // overlay
    char* tail = ws + SOBJ_B + CAPB_B;                             // 26,542,080
    uint32_t* ghist  = (uint32_t*)tail;                            // 147,456
    uint32_t* pivot  = (uint32_t*)(tail + 147456);
    uint32_t* capcnt = (uint32_t*)(tail + 147456 + 576);
    uint32_t* mode   = (uint32_t*)(tail + 147456 + 1152);
    float* sel_box   = (float*)(tail + 147456 + 1728);             // 2,304,000
    float* sel_score = sel_box + (size_t)NBC * TOPK * 4;           // 576,000
    float* final_sc  = sel_score + (size_t)NBC * TOPK;             // 576,000

    hipMemsetAsync(ghist, 0, (size_t)NBC * HBINS * 4, stream);

    sobj_kernel<<<dim3(512), dim3(1024), 0, stream>>>(obj, sobj, capcnt);
    score_capture_kernel<<<dim3(BATCH * P2BLK), dim3(1024), 0, stream>>>(
        cls, sobj, ghist, capcnt, capbuf);
    pivot_kernel<<<dim3(NBC), dim3(64), 0, stream>>>(ghist, capcnt, pivot, mode);
    slow_kernel<<<dim3(NBC), dim3(256), 0, stream>>>(cls, obj, mode, pivot, capcnt, capbuf);
    sort_emit_kernel<<<dim3(NBC), dim3(1024), 0, stream>>>(capbuf, capcnt, pivot,
                                                           anchors, deltas,
                                                           sel_box, sel_score);
    mask_build_kernel<<<dim3(NBC * NMS_SUB), dim3(1024), 0, stream>>>(sel_box, gmask);
    greedy_kernel<<<dim3(NBC), dim3(1024), 0, stream>>>(gmask, sel_score, final_sc);
    final_kernel<<<dim3(BATCH), dim3(1024), 0, stream>>>(final_sc, sel_box, out);
}

// Round 5
// 449.586 us; speedup vs baseline: 4.1772x; 1.2669x over previous
//
#include <hip/hip_runtime.h>
#include <stdint.h>

#define N_ANCH 193536
#define BATCH  16
#define NCLS   9
#define NBC    (BATCH * NCLS)   // 144
#define TOPK   1000
#define SORTN  4096             // LDS sort width (per bc and per image)
#define MAXDET 100
#define KOFF   0x3C800000u      // 121 << 23; scores in (0.05,1) -> key in (0, 2^26)
#define HBINS  256
#define HSHIFT 18               // key >> 18 -> bin (0.05 -> bin 51, 1.0 -> bin 192)
#define FLOOR_BIN 166u          // score ~0.59; capture floor (correctness-safe: SLOW fallback)
#define CAPBUF 12288            // captured records per (b,c)
#define SBUF   4096             // per-block LDS staging records
#define NMS_SUB 8
#define NWORDS 16               // 1024 bits per mask row
#define MODE_FAST 1u
#define MODE_SLOW 2u
#define OVF_BIT 0x40000000u

#define NV4_IMG 435456          // per-image cls float4 count (193536*9/4)
#define P2BLK   48              // K1 blocks per image
#define EV4     9072            // float4 per K1 block (NV4_IMG / P2BLK)
#define NF4_OBJ 774144          // obj float4 count (16*193536/4)

// ---------- exact-arith helpers (mirror reference op order; no FMA contraction) ----

__device__ __forceinline__ float sigm(float x) {
#pragma clang fp contract(off)
    return 1.0f / (1.0f + expf(-x));
}

__device__ __forceinline__ uint32_t score_key(float s) {
    return (s > 0.05f) ? (__float_as_uint(s) - KOFF) : 0u;
}

__device__ __forceinline__ void decode_box(const float* __restrict__ a,
                                           const float* __restrict__ d,
                                           float* bx) {
#pragma clang fp contract(off)
    float a0 = a[0], a1 = a[1], a2 = a[2], a3 = a[3];
    float acx = (a0 + a2) * 0.5f;
    float acy = (a1 + a3) * 0.5f;
    float aw  = fmaxf(a2 - a0, 1.0f);
    float ah  = fmaxf(a3 - a1, 1.0f);
    float cx  = d[0] * aw + acx;
    float cy  = d[1] * ah + acy;
    float w = (float)exp((double)fminf(d[2], 4.0f)) * aw;
    float h = (float)exp((double)fminf(d[3], 4.0f)) * ah;
    bx[0] = cx - w * 0.5f;
    bx[1] = cy - h * 0.5f;
    bx[2] = cx + w * 0.5f;
    bx[3] = cy + h * 0.5f;
}

__device__ __forceinline__ void bitonic_desc(uint64_t* buf, int n, int tid, int nthr) {
    for (int k = 2; k <= n; k <<= 1) {
        for (int j = k >> 1; j > 0; j >>= 1) {
            for (int i = tid; i < n; i += nthr) {
                int ixj = i ^ j;
                if (ixj > i) {
                    uint64_t va = buf[i], vb = buf[ixj];
                    bool up = ((i & k) == 0);          // descending overall
                    if (up ? (va < vb) : (va > vb)) { buf[i] = vb; buf[ixj] = va; }
                }
            }
            __syncthreads();
        }
    }
}

// ---------- K0: sobj = sigmoid(obj), float4; also zero capcnt -------------------

__global__ __launch_bounds__(1024) void sobj_kernel(
    const float* __restrict__ obj, float* __restrict__ sobj,
    uint32_t* __restrict__ capcnt)
{
    int gid = blockIdx.x * 1024 + threadIdx.x;
    if (gid < NBC) capcnt[gid] = 0;
    const float4* o4 = (const float4*)obj;
    float4* s4 = (float4*)sobj;
    for (int i = gid; i < NF4_OBJ; i += gridDim.x * 1024) {
        float4 v = o4[i];
        float4 r;
        r.x = sigm(v.x); r.y = sigm(v.y); r.z = sigm(v.z); r.w = sigm(v.w);
        s4[i] = r;
    }
}

// ---------- K1: flat float4 stream -> floor-filtered hist + LDS-staged capture ---
// No per-item global atomics: wave-ballot aggregation into LDS stage, then one
// global reservation per class per block.

__global__ __launch_bounds__(1024) void score_capture_kernel(
    const float* __restrict__ cls, const float* __restrict__ sobj,
    uint32_t* __restrict__ ghist,          // [NBC][HBINS], zeroed
    uint32_t* __restrict__ capcnt,         // [NBC], zeroed
    uint64_t* __restrict__ capbuf)         // [NBC][CAPBUF]
{
    __shared__ uint32_t lh[NCLS * HBINS];  // 9 KB
    __shared__ uint64_t stage[SBUF];       // 32 KB: (k<<22)|(c<<18)|n
    __shared__ uint32_t scnt;
    __shared__ uint32_t ccnt[NCLS];
    __shared__ uint32_t cwrite[NCLS];
    const int blk = blockIdx.x, tid = threadIdx.x;
    const int b = blk / P2BLK;
    const size_t base = (size_t)b * NV4_IMG + (size_t)(blk % P2BLK) * EV4;
    const float4* c4 = (const float4*)cls;
    const int lane = tid & 63;

    for (int i = tid; i < NCLS * HBINS; i += 1024) lh[i] = 0;
    if (tid < NCLS) ccnt[tid] = 0;
    if (tid == 0) scnt = 0;
    __syncthreads();

    for (int it = 0; it < 9; ++it) {
        int off = it * 1024 + tid;
        bool inr = (off < EV4);
        int offc = inr ? off : (EV4 - 1);
        float4 v = c4[base + offc];
        uint32_t p0 = (uint32_t)((base + offc) * 4);
        float vv[4] = {v.x, v.y, v.z, v.w};
        #pragma unroll
        for (int q = 0; q < 4; ++q) {
            uint32_t p = p0 + q;
            uint32_t bn = p / 9u;
            uint32_t c = p - 9u * bn;
            float s = sigm(vv[q]) * sobj[bn];
            uint32_t k = score_key(s);
            uint32_t bin = k >> HSHIFT;
            bool cap = inr && (bin >= FLOOR_BIN);
            uint64_t m = __ballot(cap);
            if (m) {
                uint32_t tot = (uint32_t)__popcll(m);
                int fl = __ffsll((unsigned long long)m) - 1;
                uint32_t wbase = 0;
                if (lane == fl) wbase = atomicAdd(&scnt, tot);
                wbase = __shfl(wbase, fl);
                if (cap) {
                    uint32_t slot = wbase +
                        (uint32_t)__popcll(m & ((1ull << lane) - 1ull));
                    uint32_t n = bn - (uint32_t)b * N_ANCH;
                    if (slot < SBUF)
                        stage[slot] = ((uint64_t)k << 22) | ((uint64_t)c << 18)
                                    | (uint64_t)n;
                    atomicAdd(&lh[(c << 8) + bin], 1u);
                    atomicAdd(&ccnt[c], 1u);
                }
            }
        }
    }
    __syncthreads();

    const uint32_t total = scnt;
    const uint32_t nstage = min(total, (uint32_t)SBUF);
    const bool ovf = (total > SBUF);
    if (tid < NCLS) {
        uint32_t bc = (uint32_t)b * NCLS + tid;
        uint32_t cb = atomicAdd(&capcnt[bc], ccnt[tid]);   // one reservation / class
        if (ovf) atomicOr(&capcnt[bc], OVF_BIT);           // force SLOW for this image
        cwrite[tid] = cb;
    }
    __syncthreads();

    for (uint32_t i = tid; i < nstage; i += 1024) {
        uint64_t r = stage[i];
        uint32_t c = (uint32_t)(r >> 18) & 15u;
        uint32_t n = (uint32_t)(r & 0x3FFFFu);
        uint32_t k = (uint32_t)(r >> 22);
        uint32_t slot = atomicAdd(&cwrite[c], 1u);         // LDS: global slot index
        if (slot < CAPBUF)
            capbuf[(size_t)((uint32_t)b * NCLS + c) * CAPBUF + slot] =
                ((uint64_t)k << 32) | (uint64_t)(0xFFFFFFFFu - n);
    }

    for (int i = tid; i < NCLS * HBINS; i += 1024) {
        uint32_t v = lh[i];
        if (v) atomicAdd(&ghist[(size_t)b * NCLS * HBINS + i], v);
    }
}

// ---------- K2: per-(b,c) pivot bin + FAST/SLOW mode (one wave per block) --------

__global__ __launch_bounds__(64) void pivot_kernel(
    const uint32_t* __restrict__ ghist, const uint32_t* __restrict__ capcnt,
    uint32_t* __restrict__ pivot, uint32_t* __restrict__ mode)
{
    const int blk = blockIdx.x;
    const int lane = threadIdx.x;
    const uint32_t* h = ghist + (size_t)blk * HBINS;
    uint32_t h0 = h[lane * 4 + 0], h1 = h[lane * 4 + 1];
    uint32_t h2 = h[lane * 4 + 2], h3 = h[lane * 4 + 3];
    uint32_t s = h0 + h1 + h2 + h3;
    uint32_t suf = s;                          // S(4l) = count of bins >= 4l
    for (int off = 1; off < 64; off <<= 1) {
        uint32_t o = __shfl_down(suf, off);
        if (lane + off < 64) suf += o;
    }
    uint32_t sufNext = __shfl_down(suf, 1);    // S(4l+4)
    if (lane == 63) sufNext = 0;
    uint32_t S3 = sufNext + h3;
    uint32_t S2 = S3 + h2;
    uint32_t S1 = S2 + h1;
    int d = -1;
    if      (S3 >= TOPK && sufNext < TOPK) d = 4 * lane + 3;
    else if (S2 >= TOPK && S3      < TOPK) d = 4 * lane + 2;
    else if (S1 >= TOPK && S2      < TOPK) d = 4 * lane + 1;
    else if (suf >= TOPK && S1     < TOPK) d = 4 * lane + 0;
    uint64_t fmask = __ballot(d >= 0);
    if (d >= 0) {
        pivot[blk] = (uint32_t)d;              // d >= FLOOR_BIN by construction
        mode[blk] = (capcnt[blk] <= CAPBUF) ? MODE_FAST : MODE_SLOW;
    }
    if (lane == 0 && fmask == 0) mode[blk] = MODE_SLOW;  // <TOPK above floor
}

// ---------- K3: exact fallback for SLOW (b,c) (no-op on this data) ---------------

__global__ __launch_bounds__(256) void slow_kernel(
    const float* __restrict__ cls, const float* __restrict__ obj,
    const uint32_t* __restrict__ mode, uint32_t* __restrict__ pivot,
    uint32_t* __restrict__ capcnt, uint64_t* __restrict__ capbuf)
{
    const int bc = blockIdx.x;
    if (mode[bc] == MODE_FAST) return;
    __shared__ uint32_t h[HBINS];
    __shared__ uint32_t piv;
    const int tid = threadIdx.x;
    const int b = bc / NCLS, c = bc % NCLS;
    if (tid < HBINS) h[tid] = 0;
    __syncthreads();
    for (int n = tid; n < N_ANCH; n += 256) {
        float s = sigm(cls[((size_t)b * N_ANCH + n) * NCLS + c])
                * sigm(obj[(size_t)b * N_ANCH + n]);
        uint32_t k = score_key(s);
        if (k) atomicAdd(&h[k >> HSHIFT], 1u);
    }
    __syncthreads();
    if (tid == 0) {
        uint32_t cum = 0; uint32_t d = 0;
        for (int t = HBINS - 1; t >= 0; --t) {
            if (cum + h[t] >= TOPK) { d = (uint32_t)t; break; }
            cum += h[t];
        }
        piv = d; pivot[bc] = d;
        atomicExch(&capcnt[bc], 0u);
    }
    __syncthreads();
    const uint32_t pv = piv;
    for (int n = tid; n < N_ANCH; n += 256) {
        float s = sigm(cls[((size_t)b * N_ANCH + n) * NCLS + c])
                * sigm(obj[(size_t)b * N_ANCH + n]);
        uint32_t k = score_key(s);
        if (k && (k >> HSHIFT) >= pv) {
            uint32_t slot = atomicAdd(&capcnt[bc], 1u);
            if (slot < CAPBUF)
                capbuf[(size_t)bc * CAPBUF + slot] =
                    ((uint64_t)k << 32) | (uint64_t)(0xFFFFFFFFu - (uint32_t)n);
        }
    }
}

// ---------- K4: filter captured by pivot, sort, emit top-1000 + boxes ------------

__global__ __launch_bounds__(1024) void sort_emit_kernel(
    const uint64_t* __restrict__ capbuf, const uint32_t* __restrict__ capcnt,
    const uint32_t* __restrict__ pivot,
    const float* __restrict__ anchors, const float* __restrict__ deltas,
    float* __restrict__ sel_box, float* __restrict__ sel_score)
{
    __shared__ uint64_t sbuf[SORTN];        // 32 KB
    __shared__ uint32_t lcnt;
    const int blk = blockIdx.x, tid = threadIdx.x;
    const int b = blk / NCLS;
    const uint32_t cnt = min(capcnt[blk] & ~OVF_BIT, (uint32_t)CAPBUF);
    const uint32_t pv = pivot[blk];
    for (int i = tid; i < SORTN; i += 1024) sbuf[i] = 0;
    if (tid == 0) lcnt = 0;
    __syncthreads();
    for (int i = tid; (uint32_t)i < cnt; i += 1024) {
        uint64_t e = capbuf[(size_t)blk * CAPBUF + i];
        if (((uint32_t)(e >> 32) >> HSHIFT) >= pv) {
            uint32_t s = atomicAdd(&lcnt, 1u);
            if (s < SORTN) sbuf[s] = e;
        }
    }
    __syncthreads();
    const uint32_t fc = lcnt;
    const int n = (fc <= 1024u) ? 1024 : (fc <= 2048u ? 2048 : SORTN);
    bitonic_desc(sbuf, n, tid, 1024);
    if (tid < TOPK) {
        uint64_t e = sbuf[tid];
        uint32_t k = (uint32_t)(e >> 32);
        float bx[4] = {0.f, 0.f, 0.f, 0.f};
        float score = 0.f;
        if (k) {
            uint32_t idx = 0xFFFFFFFFu - (uint32_t)(e & 0xFFFFFFFFu);
            score = __uint_as_float(k + KOFF);
            decode_box(anchors + (size_t)idx * 4,
                       deltas + ((size_t)b * N_ANCH + idx) * 4, bx);
        }
        sel_score[(size_t)blk * TOPK + tid] = score;
        float* o = sel_box + ((size_t)blk * TOPK + tid) * 4;
        o[0] = bx[0]; o[1] = bx[1]; o[2] = bx[2]; o[3] = bx[3];
    }
}

// ---------- K5: suppression bitmask, column-in-register ---------------------------
// 8 sub-blocks per (b,c); 512 threads (8 waves); wave w owns column blocks
// {w, 15-w} with j-boxes in registers; row box broadcast via 2 uniform LDS reads.
// Words with j<=r entirely are pre-zeroed by hipMemsetAsync.
// bit-exact div-free compare: fl32(inter/uni) > 0.5f  <=>  inter > (0.5+2^-25)*uni

__device__ __forceinline__ bool iou_gt(const float4& rb, float ra,
                                       const float4& cb, float ca) {
#pragma clang fp contract(off)
    float xx0 = fmaxf(rb.x, cb.x);
    float yy0 = fmaxf(rb.y, cb.y);
    float xx1 = fminf(rb.z, cb.z);
    float yy1 = fminf(rb.w, cb.w);
    float iw = fmaxf(xx1 - xx0, 0.0f);
    float ih = fmaxf(yy1 - yy0, 0.0f);
    float inter = iw * ih;
    float uni = fmaxf((ra + ca) - inter, 1e-6f);
    return ((double)inter > 0x1.000001p-1 * (double)uni);
}

__global__ __launch_bounds__(512) void mask_build_kernel(
    const float* __restrict__ sel_box, uint64_t* __restrict__ gmask)
{
    __shared__ __align__(16) float4 B4[1024];   // 16 KB
    __shared__ float AR[1024];                  // 4 KB
    const int blk = blockIdx.x, tid = threadIdx.x;
    const int bc = blk >> 3, sub = blk & 7;
    const int lane = tid & 63, w = tid >> 6;    // w in [0,8)

    for (int t = tid; t < 1024; t += 512) {
        float4 bb = make_float4(0.f, 0.f, 0.f, 0.f);
        float a = 0.f;
        if (t < TOPK) {
#pragma clang fp contract(off)
            const float* p = sel_box + ((size_t)bc * TOPK + t) * 4;
            bb.x = p[0]; bb.y = p[1]; bb.z = p[2]; bb.w = p[3];
            a = (bb.z - bb.x) * (bb.w - bb.y);
        }
        B4[t] = bb; AR[t] = a;
    }
    __syncthreads();

    const int cbA = w;                // 0..7
    const int cbB = 15 - w;           // 8..15
    const int jA = cbA * 64 + lane;
    const int jB = cbB * 64 + lane;
    const float4 bA = B4[jA]; const float aA = AR[jA];
    const float4 bB = B4[jB]; const float aB = AR[jB];
    const int limA = 64 * cbA + 64;
    const int limB = 64 * cbB + 64;
    uint64_t* base = gmask + (size_t)bc * TOPK * NWORDS;

    int r = sub;
    for (; r < limA; r += 8) {                     // limA <= 512 < TOPK
        float4 rb = B4[r]; float ra = AR[r];
        bool pA = (jA > r && jA < TOPK) && iou_gt(rb, ra, bA, aA);
        uint64_t mA = __ballot(pA);
        bool pB = (jB > r && jB < TOPK) && iou_gt(rb, ra, bB, aB);
        uint64_t mB = __ballot(pB);
        if (lane == 0) {
            base[(size_t)r * NWORDS + cbA] = mA;
            base[(size_t)r * NWORDS + cbB] = mB;
        }
    }
    for (; r < limB && r < TOPK; r += 8) {
        float4 rb = B4[r]; float ra = AR[r];
        bool pB = (jB > r && jB < TOPK) && iou_gt(rb, ra, bB, aB);
        uint64_t mB = __ballot(pB);
        if (lane == 0) base[(size_t)r * NWORDS + cbB] = mB;
    }
}

// ---------- K6: greedy scan over bitmask (LDS-staged, one wave, ring prefetch) ---

__global__ __launch_bounds__(1024) void greedy_kernel(
    const uint64_t* __restrict__ gmask, const float* __restrict__ sel_score,
    float* __restrict__ final_score)
{
    __shared__ uint64_t lmask[TOPK * NWORDS];   // 125 KB
    __shared__ uint64_t remOut[NWORDS];
    const int blk = blockIdx.x, tid = threadIdx.x;
    for (int i = tid; i < TOPK * NWORDS; i += 1024)
        lmask[i] = gmask[(size_t)blk * TOPK * NWORDS + i];
    __syncthreads();

    if (tid < 64) {
        const int lane = tid;
        uint64_t rem = 0;                 // lane w < 16 owns removed-word w
        uint64_t ring[16];
        #pragma unroll
        for (int u = 0; u < 16; ++u)
            ring[u] = (lane < NWORDS) ? lmask[u * NWORDS + lane] : 0;
        for (int ib = 0; ib < TOPK; ib += 16) {
            #pragma unroll
            for (int u = 0; u < 16; ++u) {
                int i = ib + u;
                if (i < TOPK) {
                    uint64_t row = ring[u];
                    int ipf = i + 16;
                    ring[u] = (lane < NWORDS && ipf < TOPK) ? lmask[ipf * NWORDS + lane] : 0;
                    int wi = i >> 6;
                    uint32_t lo = (uint32_t)__builtin_amdgcn_readlane((int)(uint32_t)rem, wi);
                    uint32_t hi = (uint32_t)__builtin_amdgcn_readlane((int)(uint32_t)(rem >> 32), wi);
                    uint64_t wv = ((uint64_t)hi << 32) | lo;
                    if (!((wv >> (i & 63)) & 1ull)) rem |= row;
                }
            }
        }
        if (lane < NWORDS) remOut[lane] = rem;
    }
    __syncthreads();

    if (tid < TOPK) {
        bool kept = !((remOut[tid >> 6] >> (tid & 63)) & 1ull);
        float s = sel_score[(size_t)blk * TOPK + tid];
        final_score[(size_t)blk * TOPK + tid] = (kept && s > 0.05f) ? s : 0.0f;
    }
}

// ---------- K7: per-image top-100 (hist-select + bitonic; exact tie semantics) ---

__global__ __launch_bounds__(1024) void final_kernel(
    const float* __restrict__ final_score, const float* __restrict__ sel_box,
    float* __restrict__ out)                // [BATCH][MAXDET][6]
{
    __shared__ float sc[NCLS * TOPK];       // 36 KB
    __shared__ uint32_t h[4096];            // 16 KB
    __shared__ uint32_t chunk[1024];
    __shared__ uint64_t sbuf[SORTN];        // 32 KB
    __shared__ int sh_d, sh_fb;
    __shared__ uint32_t cnt;
    const int b = blockIdx.x, tid = threadIdx.x;

    for (int i = tid; i < 4096; i += 1024) h[i] = 0;
    for (int t = tid; t < NCLS * TOPK; t += 1024)
        sc[t] = final_score[(size_t)b * NCLS * TOPK + t];
    if (tid == 0) cnt = 0;
    __syncthreads();

    for (int t = tid; t < NCLS * TOPK; t += 1024) {
        uint32_t bits = __float_as_uint(sc[t]);
        if (bits) atomicAdd(&h[bits >> HSHIFT], 1u);
    }
    __syncthreads();
    chunk[tid] = h[tid * 4] + h[tid * 4 + 1] + h[tid * 4 + 2] + h[tid * 4 + 3];
    __syncthreads();
    if (tid == 0) {
        int d = -1; uint32_t cum = 0;
        for (int t = 1023; t >= 0; --t) {
            if (cum + chunk[t] >= MAXDET) {
                for (int j = 3; j >= 0; --j) {
                    uint32_t v = h[t * 4 + j];
                    if (cum + v >= MAXDET) { d = t * 4 + j; goto found; }
                    cum += v;
                }
            }
            cum += chunk[t];
        }
found:
        if (d < 0) { sh_d = 0; sh_fb = 1; }
        else       { sh_d = d; sh_fb = 0; }
    }
    __syncthreads();
    const int d = sh_d, fb = sh_fb;

    for (int t = tid; t < NCLS * TOPK; t += 1024) {
        uint32_t bits = __float_as_uint(sc[t]);
        bool take = fb ? (bits != 0 || t < 1024)
                       : (bits != 0 && (bits >> HSHIFT) >= (uint32_t)d);
        if (take) {
            uint32_t slot = atomicAdd(&cnt, 1u);
            if (slot < SORTN)
                sbuf[slot] = ((uint64_t)bits << 32) | (uint64_t)(0xFFFFFFFFu - (uint32_t)t);
        }
    }
    __syncthreads();
    uint32_t c2 = min(cnt, (uint32_t)SORTN);
    for (int i = tid; i < SORTN; i += 1024)
        if ((uint32_t)i >= c2) sbuf[i] = 0;
    __syncthreads();
    const int n = (c2 <= 512u) ? 512 : (c2 <= 1024u) ? 1024 : (c2 <= 2048u ? 2048 : SORTN);
    bitonic_desc(sbuf, n, tid, 1024);

    if (tid < MAXDET) {
        uint64_t e = sbuf[tid];
        uint32_t bits = (uint32_t)(e >> 32);
        uint32_t flat = 0xFFFFFFFFu - (uint32_t)(e & 0xFFFFFFFFu);
        float bx[4] = {0.f, 0.f, 0.f, 0.f};
        float sval = 0.f, lab = 0.f;
        if (flat < NCLS * TOPK) {
            const float* bp = sel_box + ((size_t)b * NCLS * TOPK + flat) * 4;
            bx[0] = bp[0]; bx[1] = bp[1]; bx[2] = bp[2]; bx[3] = bp[3];
            sval = __uint_as_float(bits);
            lab = (float)(flat / TOPK);
        }
        float* o = out + ((size_t)b * MAXDET + tid) * 6;
        o[0] = bx[0]; o[1] = bx[1]; o[2] = bx[2]; o[3] = bx[3];
        o[4] = sval;  o[5] = lab;
    }
}

// ---------------------------------- launcher -----------------------------------

extern "C" void kernel_launch(void* const* d_in, const int* in_sizes, int n_in,
                              void* d_out, int out_size, void* d_ws, size_t ws_size,
                              hipStream_t stream) {
    const float* anchors = (const float*)d_in[0];
    const float* deltas  = (const float*)d_in[1];
    const float* cls     = (const float*)d_in[2];
    const float* obj     = (const float*)d_in[3];
    float* out = (float*)d_out;

    // workspace layout (~30.2 MB).
    //   [0, 12.39M)          sobj        (dies after K1)
    //   [12.39M, 26.55M)     capbuf      (dies after K4)
    //   [0, 18.44M)          gmask       (overlay; born after K4 via memset)
    //   persistent tail: ghist, pivot/capcnt/mode, sel_box, sel_score, final_sc
    char* ws = (char*)d_ws;
    const size_t SOBJ_B   = (size_t)BATCH * N_ANCH * 4;            // 12,386,304
    const size_t CAPB_B   = (size_t)NBC * CAPBUF * 8;              // 14,155,776
    const size_t GMASK_B  = (size_t)NBC * TOPK * NWORDS * 8;       // 18,432,000
    float*    sobj   = (float*)ws;
    uint64_t* capbuf = (uint64_t*)(ws + SOBJ_B);
    uint64_t* gmask  = (uint64_t*)ws;                              // overlay
    char* tail = ws + SOBJ_B + CAPB_B;                             // 26,542,080
    uint32_t* ghist  = (uint32_t*)tail;                            // 147,456
    uint32_t* pivot  = (uint32_t*)(tail + 147456);
    uint32_t* capcnt = (uint32_t*)(tail + 147456 + 576);
    uint32_t* mode   = (uint32_t*)(tail + 147456 + 1152);
    float* sel_box   = (float*)(tail + 147456 + 1728);             // 2,304,000
    float* sel_score = sel_box + (size_t)NBC * TOPK * 4;           // 576,000
    float* final_sc  = sel_score + (size_t)NBC * TOPK;             // 576,000

    hipMemsetAsync(ghist, 0, (size_t)NBC * HBINS * 4, stream);

    sobj_kernel<<<dim3(512), dim3(1024), 0, stream>>>(obj, sobj, capcnt);
    score_capture_kernel<<<dim3(BATCH * P2BLK), dim3(1024), 0, stream>>>(
        cls, sobj, ghist, capcnt, capbuf);
    pivot_kernel<<<dim3(NBC), dim3(64), 0, stream>>>(ghist, capcnt, pivot, mode);
    slow_kernel<<<dim3(NBC), dim3(256), 0, stream>>>(cls, obj, mode, pivot, capcnt, capbuf);
    sort_emit_kernel<<<dim3(NBC), dim3(1024), 0, stream>>>(capbuf, capcnt, pivot,
                                                           anchors, deltas,
                                                           sel_box, sel_score);
    hipMemsetAsync(gmask, 0, GMASK_B, stream);   // zero j<=r words (sobj/capbuf dead)
    mask_build_kernel<<<dim3(NBC * NMS_SUB), dim3(512), 0, stream>>>(sel_box, gmask);
    greedy_kernel<<<dim3(NBC), dim3(1024), 0, stream>>>(gmask, sel_score, final_sc);
    final_kernel<<<dim3(BATCH), dim3(1024), 0, stream>>>(final_sc, sel_box, out);
}